// Round 3
// baseline (381.666 us; speedup 1.0000x reference)
//
#include <hip/hip_runtime.h>

#define S_LEN 4096
#define DIM   256
#define QBLK  64
#define KVBLK 64

typedef __attribute__((ext_vector_type(4))) float f32x4;
typedef __attribute__((ext_vector_type(8))) short bf16x8;
typedef __attribute__((ext_vector_type(4))) unsigned short u16x4;
typedef __attribute__((ext_vector_type(8))) unsigned short u16x8;

// fp32 -> bf16 round-to-nearest-even
__device__ __forceinline__ unsigned short f2bf(float x) {
    union { float f; unsigned u; } v; v.f = x;
    unsigned r = v.u + 0x7FFFu + ((v.u >> 16) & 1u);
    return (unsigned short)(r >> 16);
}

// DIRECT=true: normalize and write O in-kernel (no workspace / no combine).
template<bool DIRECT>
__global__ __launch_bounds__(256, 2) void attn_part(
        const float* __restrict__ Qg, const float* __restrict__ Kg,
        const float* __restrict__ Vg, float* __restrict__ OP,
        float* __restrict__ ML, float* __restrict__ Og,
        int CH, int perbatch) {
    __shared__ unsigned short Ksh[KVBLK * DIM];      // [64][256] bf16, swz
    __shared__ unsigned short VshT[DIM * KVBLK];     // [256][64] bf16 (V^T), swz
    __shared__ unsigned short Psh[4][16 * KVBLK];    // per-wave [16][64] bf16, swz

    const int tid = threadIdx.x;
    const int w   = tid >> 6;
    const int l   = tid & 63;
    const int l15 = l & 15;
    const int lg  = l >> 4;

    // ---- decode blockIdx -> (batch, q-tile, kv-chunk), balanced enumeration ----
    const int id = blockIdx.x;
    const int b  = id / perbatch;
    int r = id - b * perbatch;
    int g = 0;
    while (r >= CH * (g + 1)) { r -= CH * (g + 1); ++g; }
    const int qt    = g * CH + r / (g + 1);
    const int chunk = r - (r / (g + 1)) * (g + 1);
    const int t0 = chunk * CH;
    const int t1 = min((chunk + 1) * CH, qt + 1);
    const int qbase = qt * QBLK;

    // ---------- Q fragments (16 rows/wave, scale 1/16 folded) ----------
    const int qrow = qbase + w * 16 + l15;
    const float* qp = Qg + (size_t)(b * S_LEN + qrow) * DIM + lg * 8;
    bf16x8 qf[8];
#pragma unroll
    for (int ks = 0; ks < 8; ++ks) {
        f32x4 a = *(const f32x4*)(qp + ks * 32);
        f32x4 c = *(const f32x4*)(qp + ks * 32 + 4);
        bf16x8 f;
        f[0] = (short)f2bf(a[0] * 0.0625f); f[1] = (short)f2bf(a[1] * 0.0625f);
        f[2] = (short)f2bf(a[2] * 0.0625f); f[3] = (short)f2bf(a[3] * 0.0625f);
        f[4] = (short)f2bf(c[0] * 0.0625f); f[5] = (short)f2bf(c[1] * 0.0625f);
        f[6] = (short)f2bf(c[2] * 0.0625f); f[7] = (short)f2bf(c[3] * 0.0625f);
        qf[ks] = f;
    }

    f32x4 acc[16];
#pragma unroll
    for (int i = 0; i < 16; ++i) acc[i] = (f32x4)0.0f;
    float mrun[4] = {-1e30f, -1e30f, -1e30f, -1e30f};
    float lrun[4] = {0.f, 0.f, 0.f, 0.f};

    const float* Kb = Kg + (size_t)b * S_LEN * DIM;
    const float* Vb = Vg + (size_t)b * S_LEN * DIM;

    for (int t = t0; t < t1; ++t) {
        // ---------------- stage K tile (row-major, swizzled) ----------------
        {
            const float* src = Kb + (size_t)t * KVBLK * DIM;
#pragma unroll
            for (int it = 0; it < 16; ++it) {
                int row = 4 * it + w;
                int col = 4 * l;
                f32x4 x = *(const f32x4*)(src + row * DIM + col);
                u16x4 h;
                h.x = f2bf(x[0]); h.y = f2bf(x[1]); h.z = f2bf(x[2]); h.w = f2bf(x[3]);
                unsigned off = (unsigned)(row * 512 + col * 2);
                off ^= (unsigned)((row & 7) << 4);
                *(u16x4*)((char*)Ksh + off) = h;
            }
            // ------- stage V transposed: 16B writes, conflict-free -------
            const float* vs = Vb + (size_t)t * KVBLK * DIM;
#pragma unroll
            for (int gq = 0; gq < 8; ++gq) {
                float x0 = vs[(8 * gq + 0) * DIM + tid];
                float x1 = vs[(8 * gq + 1) * DIM + tid];
                float x2 = vs[(8 * gq + 2) * DIM + tid];
                float x3 = vs[(8 * gq + 3) * DIM + tid];
                float x4 = vs[(8 * gq + 4) * DIM + tid];
                float x5 = vs[(8 * gq + 5) * DIM + tid];
                float x6 = vs[(8 * gq + 6) * DIM + tid];
                float x7 = vs[(8 * gq + 7) * DIM + tid];
                u16x8 h;
                h[0] = f2bf(x0); h[1] = f2bf(x1); h[2] = f2bf(x2); h[3] = f2bf(x3);
                h[4] = f2bf(x4); h[5] = f2bf(x5); h[6] = f2bf(x6); h[7] = f2bf(x7);
                unsigned off = (unsigned)(tid * 128 + gq * 16);
                off ^= (unsigned)((tid & 7) << 4);
                *(u16x8*)((char*)VshT + off) = h;
            }
        }
        __syncthreads();

        // ---------------- S = (Q*scale) K^T ----------------
        f32x4 sacc[4];
#pragma unroll
        for (int j = 0; j < 4; ++j) sacc[j] = (f32x4)0.0f;
#pragma unroll
        for (int ks = 0; ks < 8; ++ks) {
#pragma unroll
            for (int jt = 0; jt < 4; ++jt) {
                int j = jt * 16 + l15;
                unsigned off = (unsigned)(j * 512 + (ks * 32 + lg * 8) * 2);
                off ^= (unsigned)((j & 7) << 4);
                bf16x8 kb = *(const bf16x8*)((const char*)Ksh + off);
                sacc[jt] = __builtin_amdgcn_mfma_f32_16x16x32_bf16(qf[ks], kb, sacc[jt], 0, 0, 0);
            }
        }

        // ---------------- causal mask (strict: j < i) on diagonal tile ----------------
        if (t == qt) {
#pragma unroll
            for (int jt = 0; jt < 4; ++jt)
#pragma unroll
                for (int rr = 0; rr < 4; ++rr) {
                    int jl = jt * 16 + l15;
                    int ml_ = w * 16 + lg * 4 + rr;
                    if (jl >= ml_) sacc[jt][rr] = -3e38f;
                }
        }

        // ---------------- online softmax ----------------
        float pex[4][4];
        float corr[4];
#pragma unroll
        for (int rr = 0; rr < 4; ++rr) {
            float mx = fmaxf(fmaxf(sacc[0][rr], sacc[1][rr]), fmaxf(sacc[2][rr], sacc[3][rr]));
            mx = fmaxf(mx, __shfl_xor(mx, 1));
            mx = fmaxf(mx, __shfl_xor(mx, 2));
            mx = fmaxf(mx, __shfl_xor(mx, 4));
            mx = fmaxf(mx, __shfl_xor(mx, 8));
            float mnew = fmaxf(mrun[rr], mx);
            corr[rr] = __expf(mrun[rr] - mnew);
            mrun[rr] = mnew;
            float s0 = __expf(sacc[0][rr] - mnew);
            float s1 = __expf(sacc[1][rr] - mnew);
            float s2 = __expf(sacc[2][rr] - mnew);
            float s3 = __expf(sacc[3][rr] - mnew);
            pex[0][rr] = s0; pex[1][rr] = s1; pex[2][rr] = s2; pex[3][rr] = s3;
            float ls = s0 + s1 + s2 + s3;
            ls += __shfl_xor(ls, 1);
            ls += __shfl_xor(ls, 2);
            ls += __shfl_xor(ls, 4);
            ls += __shfl_xor(ls, 8);
            lrun[rr] = lrun[rr] * corr[rr] + ls;
        }
#pragma unroll
        for (int nt = 0; nt < 16; ++nt)
#pragma unroll
            for (int rr = 0; rr < 4; ++rr) acc[nt][rr] *= corr[rr];

        // ---------------- P -> per-wave LDS ----------------
        {
            char* pw = (char*)&Psh[w][0];
#pragma unroll
            for (int jt = 0; jt < 4; ++jt)
#pragma unroll
                for (int rr = 0; rr < 4; ++rr) {
                    int m = lg * 4 + rr;
                    unsigned off = (unsigned)(m * 128 + (jt * 16 + l15) * 2);
                    off ^= (unsigned)((m & 7) << 4);
                    *(unsigned short*)(pw + off) = f2bf(pex[jt][rr]);
                }
        }

        // ---------------- O += P V ----------------
#pragma unroll
        for (int ks = 0; ks < 2; ++ks) {
            unsigned poff = (unsigned)(l15 * 128 + ks * 64 + lg * 16);
            poff ^= (unsigned)((l15 & 7) << 4);
            bf16x8 pa = *(const bf16x8*)((const char*)&Psh[w][0] + poff);
#pragma unroll
            for (int nt = 0; nt < 16; ++nt) {
                unsigned voff = (unsigned)((nt * 16 + l15) * 128 + ks * 64 + lg * 16);
                voff ^= (unsigned)((l15 & 7) << 4);
                bf16x8 vbf = *(const bf16x8*)((const char*)VshT + voff);
                acc[nt] = __builtin_amdgcn_mfma_f32_16x16x32_bf16(pa, vbf, acc[nt], 0, 0, 0);
            }
        }
        __syncthreads();
    }

    if (DIRECT) {
        float rl[4];
#pragma unroll
        for (int rr = 0; rr < 4; ++rr) rl[rr] = (lrun[rr] > 0.f) ? (1.0f / lrun[rr]) : 0.f;
        float* ob = Og + (size_t)(b * S_LEN + qbase + w * 16) * DIM;
#pragma unroll
        for (int nt = 0; nt < 16; ++nt)
#pragma unroll
            for (int rr = 0; rr < 4; ++rr) {
                int row = lg * 4 + rr;
                ob[(size_t)row * DIM + nt * 16 + l15] = acc[nt][rr] * rl[rr];
            }
    } else {
        // unnormalized partial + (m,l) per row
        float* op = OP + (size_t)id * (QBLK * DIM) + (size_t)(w * 16) * DIM;
#pragma unroll
        for (int nt = 0; nt < 16; ++nt)
#pragma unroll
            for (int rr = 0; rr < 4; ++rr) {
                int row = lg * 4 + rr;
                op[(size_t)row * DIM + nt * 16 + l15] = acc[nt][rr];
            }
        if (l15 == 0) {
            float* mlp = ML + (size_t)id * 128;
#pragma unroll
            for (int rr = 0; rr < 4; ++rr) {
                int row = w * 16 + lg * 4 + rr;
                mlp[row * 2]     = mrun[rr];
                mlp[row * 2 + 1] = lrun[rr];
            }
        }
    }
}

// one block per (b, qt, row-quarter); merges C chunk partials
__global__ __launch_bounds__(256) void attn_combine(
        const float* __restrict__ OP, const float* __restrict__ ML,
        float* __restrict__ Og, int CH, int perbatch) {
    const int id = blockIdx.x;           // (b*64+qt)*4 + rg
    const int rg = id & 3;
    const int bq = id >> 2;
    const int b  = bq >> 6;
    const int qt = bq & 63;
    const int g  = qt / CH;
    const int C  = g + 1;
    const int sb = b * perbatch + CH * g * (g + 1) / 2 + (qt - g * CH) * C;
    const int d  = threadIdx.x;

    float* outb = Og + ((size_t)(b * S_LEN + qt * QBLK)) * DIM;
    for (int row = rg * 16; row < rg * 16 + 16; ++row) {
        float M = -1e30f;
        for (int c = 0; c < C; ++c)
            M = fmaxf(M, ML[(size_t)(sb + c) * 128 + row * 2]);
        float L = 0.f, o = 0.f;
        for (int c = 0; c < C; ++c) {
            float mm = ML[(size_t)(sb + c) * 128 + row * 2];
            float ll = ML[(size_t)(sb + c) * 128 + row * 2 + 1];
            float s  = __expf(mm - M);
            L += ll * s;
            o += s * OP[((size_t)(sb + c) * QBLK + row) * DIM + d];
        }
        float rl = (L > 0.f) ? (1.0f / L) : 0.f;
        outb[(size_t)row * DIM + d] = o * rl;
    }
}

extern "C" void kernel_launch(void* const* d_in, const int* in_sizes, int n_in,
                              void* d_out, int out_size, void* d_ws, size_t ws_size,
                              hipStream_t stream) {
    const float* q = (const float*)d_in[0];
    const float* k = (const float*)d_in[1];
    const float* v = (const float*)d_in[2];
    float* o = (float*)d_out;

    // pick chunk size (KV tiles per block) that fits the workspace
    const size_t slotBytes = (size_t)(QBLK * DIM + 2 * QBLK) * 4;  // 66048
    int CH = 64;
    for (int c : {8, 16, 32}) {
        int NG = 64 / c;
        int nblk = 4 * 32 * (NG + 1);
        if (ws_size >= (size_t)nblk * slotBytes) { CH = c; break; }
    }

    if (CH == 64) {
        dim3 grid(256), block(256);
        hipLaunchKernelGGL((attn_part<true>), grid, block, 0, stream,
                           q, k, v, (float*)nullptr, (float*)nullptr, o, 64, 64);
    } else {
        int NG = 64 / CH;
        int perbatch = 32 * (NG + 1);
        int nblk = 4 * perbatch;
        float* OP = (float*)d_ws;
        float* ML = OP + (size_t)nblk * (QBLK * DIM);
        dim3 block(256);
        hipLaunchKernelGGL((attn_part<false>), dim3(nblk), block, 0, stream,
                           q, k, v, OP, ML, o, CH, perbatch);
        hipLaunchKernelGGL(attn_combine, dim3(256 * 4), block, 0, stream,
                           OP, ML, o, CH, perbatch);
    }
}